// Round 7
// baseline (995.322 us; speedup 1.0000x reference)
//
#include <hip/hip_runtime.h>

typedef _Float16 f16;
typedef _Float16 f16x8 __attribute__((ext_vector_type(8)));
typedef float f32x16 __attribute__((ext_vector_type(16)));

#define TM 128   // block M tile
#define TN 256   // block N tile
#define BK 64

__device__ __forceinline__ void async_cp16(const void* g, void* l) {
  __builtin_amdgcn_global_load_lds(
      (const __attribute__((address_space(1))) void*)g,
      (__attribute__((address_space(3))) void*)l, 16, 0, 0);
}

// C = A @ Bt^T, A [M][K] f16 row-major, Bt [N][K] f16 row-major.
// Block 128x256, 4 waves of 64x128 (2x4 of 32x32 MFMA accs), BK=64,
// LDS 48KB, launch_bounds(256,2) -> 2 blocks/CU (R6: 166us, MfmaUtil 36.5%).
//
// AMODE 0: A staged via global_load_lds DMA (raw f16).
// AMODE 1: A = relu(LN(Y)*g+b) applied on the fly during staging:
//          regular 16B loads + packed-f16 math + ds_write_b128 into the
//          IDENTICAL swizzled LDS layout. Row stats come from stats_in
//          (Sum y, Sum y^2 per row), filled by the PRODUCER's epilogue via
//          device-scope atomicAdd; the kernel boundary is the release/
//          acquire point (no per-block __threadfence -- R3 lesson).
// EPI 0: C = f16(relu(acc + bias[col]))   (layer 0)
// EPI 1: C = f16(acc)                      (pre-LN layers)
// STATS 1: epilogue accumulates per-row Sum/SumSq of acc into stats_out.
// NOTE: SQ_LDS_BANK_CONFLICT saturates at 2^24 -- do not trust it.
template <int AMODE, int EPI, int STATS>
__global__ __launch_bounds__(256, 2) void gemm_f16(
    const f16* __restrict__ A, const f16* __restrict__ Bt,
    const float* __restrict__ bias, const float2* __restrict__ stats_in,
    const f16* __restrict__ gh, const f16* __restrict__ beh,
    float* __restrict__ stats_out, f16* __restrict__ C, int M, int N, int K) {
  __shared__ alignas(16) f16 sA[TM][BK];
  __shared__ alignas(16) f16 sB[TN][BK];
  const int tid = threadIdx.x;
  const int lane = tid & 63;
  const int wave = tid >> 6;

  // XCD-aware remap (R2-verified: FETCH 530 -> 112 MB): the 4 blocks
  // sharing an A-panel get ids spaced 8 apart -> same XCD, L2-resident.
  int mt, nt;
  if (gridDim.x == 4 && gridDim.y == 512) {
    const int id = blockIdx.y * 4 + blockIdx.x;
    nt = (id >> 3) & 3;
    mt = (id & 7) * 64 + (id >> 5);
  } else {
    nt = blockIdx.x;
    mt = blockIdx.y;
  }
  const long long bm = (long long)mt * TM;
  const long long bn = (long long)nt * TN;

  const int wm = (wave & 1) * 64;    // wave's 64-row band
  const int wn = (wave >> 1) * 128;  // wave's 128-col band
  const int l31 = lane & 31;
  const int half = lane >> 5;

  // Block-uniform bases + 32-bit lane offsets (R6 VGPR diet).
  const f16* const Abase = A + bm * (long long)K;
  const f16* const Bbase = Bt + bn * (long long)K;
  // A chunk geometry: chunk = wave*256 + i*64 + lane; ml = chunk>>3;
  // kcg = (chunk&7)^(ml&7). Both (chunk&7) and (ml&7) are i-invariant.
  const int aKc = (lane & 7) ^ ((wave * 32 + (lane >> 3)) & 7);
  int aOff[4], bOff[8];
#pragma unroll
  for (int i = 0; i < 4; ++i) {
    const int ml = wave * 32 + i * 8 + (lane >> 3);
    aOff[i] = ml * K + aKc * 8;
  }
#pragma unroll
  for (int i = 0; i < 8; ++i) {
    const int chunk = wave * 512 + i * 64 + lane;
    const int ml = chunk >> 3;
    const int kc = (chunk & 7) ^ (ml & 7);
    bOff[i] = ml * K + kc * 8;
  }

  // AMODE 1: per-thread row stats for the 4 A rows this thread stages.
  f16 rstdh[4], nmrh[4];
  if (AMODE == 1) {
#pragma unroll
    for (int i = 0; i < 4; ++i) {
      const int ml = wave * 32 + i * 8 + (lane >> 3);
      const float2 sv = stats_in[bm + ml];
      const float mean = sv.x * (1.f / 1024.f);
      const float var = fmaxf(sv.y * (1.f / 1024.f) - mean * mean, 0.f);
      const float rs = rsqrtf(var + 1e-6f);
      rstdh[i] = (f16)rs;
      nmrh[i] = (f16)(-mean * rs);
    }
  }

  f32x16 acc[2][4] = {};  // 2(m) x 4(n) of 32x32 tiles

  const int kIters = K / BK;
  for (int kt = 0; kt < kIters; ++kt) {
    const int k0 = kt * BK;
    if (AMODE == 0) {
#pragma unroll
      for (int i = 0; i < 4; ++i)
        async_cp16(Abase + aOff[i] + k0, &sA[0][0] + (wave * 256 + i * 64) * 8);
    } else {
      // LN-on-the-fly A staging (packed f16): same bytes, same LDS slots.
      const f16x8 g8 = *(const f16x8*)(gh + k0 + aKc * 8);
      const f16x8 be8 = *(const f16x8*)(beh + k0 + aKc * 8);
#pragma unroll
      for (int i = 0; i < 4; ++i) {
        f16x8 y = *(const f16x8*)(Abase + aOff[i] + k0);
        f16x8 t = y * rstdh[i] + nmrh[i];  // (y - mean) * rstd
        f16x8 o = t * g8 + be8;
#pragma unroll
        for (int e = 0; e < 8; ++e) o[e] = o[e] > (f16)0.f ? o[e] : (f16)0.f;
        *(f16x8*)(&sA[0][0] + (wave * 256 + i * 64 + lane) * 8) = o;
      }
    }
#pragma unroll
    for (int i = 0; i < 8; ++i)
      async_cp16(Bbase + bOff[i] + k0, &sB[0][0] + (wave * 512 + i * 64) * 8);
    __syncthreads();

#pragma unroll
    for (int s = 0; s < 4; ++s) {  // K=16 per step
      // A-operand 32x32x16: m = lane&31, k = (lane>>5)*8 + j (B mirrors, n).
      const int csw = ((s * 2 + half) ^ (lane & 7)) * 8;
      f16x8 af[2], bf[4];
#pragma unroll
      for (int i = 0; i < 2; ++i) af[i] = *(const f16x8*)&sA[wm + i * 32 + l31][csw];
#pragma unroll
      for (int j = 0; j < 4; ++j) bf[j] = *(const f16x8*)&sB[wn + j * 32 + l31][csw];
#pragma unroll
      for (int i = 0; i < 2; ++i)
#pragma unroll
        for (int j = 0; j < 4; ++j)
          acc[i][j] = __builtin_amdgcn_mfma_f32_32x32x16_f16(af[i], bf[j],
                                                             acc[i][j], 0, 0, 0);
    }
    __syncthreads();
  }

  // Epilogue. 32x32 C/D: col = lane&31, row = (reg&3) + 8*(reg>>2) + 4*(lane>>5)
  // (m74/m101-verified; R3-R6 confirmed end-to-end).
  if (STATS) {
#pragma unroll
    for (int i = 0; i < 2; ++i)
#pragma unroll
      for (int reg = 0; reg < 16; ++reg) {
        const long long rowg =
            bm + wm + i * 32 + (reg & 3) + 8 * (reg >> 2) + 4 * half;
        float e1 = 0.f, e2 = 0.f;
#pragma unroll
        for (int j = 0; j < 4; ++j) {
          const long long colg = bn + wn + j * 32 + l31;
          const float v = acc[i][j][reg];
          C[rowg * N + colg] = (f16)v;
          e1 += v;
          e2 += v * v;
        }
        // reduce over the 32 lanes of this half (xor on bits 0..4 only)
#pragma unroll
        for (int off = 16; off >= 1; off >>= 1) {
          e1 += __shfl_xor(e1, off);
          e2 += __shfl_xor(e2, off);
        }
        if (l31 == 0) {
          atomicAdd(&stats_out[2 * rowg], e1);
          atomicAdd(&stats_out[2 * rowg + 1], e2);
        }
      }
  } else {
#pragma unroll
    for (int i = 0; i < 2; ++i)
#pragma unroll
      for (int j = 0; j < 4; ++j) {
        const long long colg = bn + wn + j * 32 + l31;
        float bval = 0.f;
        if (EPI == 0) bval = bias[colg];
#pragma unroll
        for (int reg = 0; reg < 16; ++reg) {
          const long long rowg =
              bm + wm + i * 32 + (reg & 3) + 8 * (reg >> 2) + 4 * half;
          float v = acc[i][j][reg];
          if (EPI == 0) v = fmaxf(v + bval, 0.f);
          C[rowg * N + colg] = (f16)v;
        }
      }
  }
}

// Fused layer-3 LN + relu + output dot (R2-proven):
// out[row] = relu(dot(relu(LN(y)*g+b), Wout) + bout)
__global__ __launch_bounds__(256) void ln_relu_out_kernel(
    const f16* __restrict__ Y, const float* __restrict__ g,
    const float* __restrict__ b, const float* __restrict__ Wout,
    const float* __restrict__ bout, float* __restrict__ out) {
  const int lane = threadIdx.x & 63;
  const int wave = threadIdx.x >> 6;
  const long long row = (long long)blockIdx.x * 4 + wave;
  const f16* y = Y + row * 1024;
  float x[16];
  float s1 = 0.f, s2 = 0.f;
#pragma unroll
  for (int p = 0; p < 2; ++p) {
    f16x8 v = *(const f16x8*)(y + p * 512 + lane * 8);
#pragma unroll
    for (int e = 0; e < 8; ++e) {
      const float f = (float)v[e];
      x[p * 8 + e] = f;
      s1 += f;
      s2 += f * f;
    }
  }
#pragma unroll
  for (int off = 32; off >= 1; off >>= 1) {
    s1 += __shfl_xor(s1, off);
    s2 += __shfl_xor(s2, off);
  }
  const float mean = s1 * (1.f / 1024.f);
  const float var = fmaxf(s2 * (1.f / 1024.f) - mean * mean, 0.f);
  const float inv = rsqrtf(var + 1e-6f);
  float dot = 0.f;
#pragma unroll
  for (int p = 0; p < 2; ++p) {
#pragma unroll
    for (int e = 0; e < 8; ++e) {
      const int c = p * 512 + lane * 8 + e;
      const float v = fmaxf((x[p * 8 + e] - mean) * inv * g[c] + b[c], 0.f);
      dot += v * Wout[c];
    }
  }
#pragma unroll
  for (int off = 32; off >= 1; off >>= 1) dot += __shfl_xor(dot, off);
  if (lane == 0) out[row] = fmaxf(dot + bout[0], 0.f);
}

__global__ __launch_bounds__(256) void zero_f32_kernel(float* __restrict__ p,
                                                       int n) {
  const int i = (blockIdx.x * 256 + threadIdx.x) * 4;
  if (i < n) *(float4*)(p + i) = float4{0.f, 0.f, 0.f, 0.f};
}

// fp32 -> f16 elementwise (8 per thread)
__global__ __launch_bounds__(256) void cvt_f16_kernel(const float* __restrict__ X,
                                                      f16* __restrict__ Y,
                                                      long long n) {
  const long long i = ((long long)blockIdx.x * 256 + threadIdx.x) * 8;
  if (i >= n) return;
  const float4* X4 = (const float4*)(X + i);
  const float4 a = X4[0], c = X4[1];
  f16x8 o;
  o[0] = (f16)a.x; o[1] = (f16)a.y; o[2] = (f16)a.z; o[3] = (f16)a.w;
  o[4] = (f16)c.x; o[5] = (f16)c.y; o[6] = (f16)c.z; o[7] = (f16)c.w;
  *(f16x8*)(Y + i) = o;
}

// Convert 4 fp32 arrays of 1024 (g1,be1,g2,be2) to f16, one block of 1024.
__global__ void cvt_gb_kernel(const float* __restrict__ g1,
                              const float* __restrict__ be1,
                              const float* __restrict__ g2,
                              const float* __restrict__ be2,
                              f16* __restrict__ o) {
  const int t = threadIdx.x;
  o[t] = (f16)g1[t];
  o[1024 + t] = (f16)be1[t];
  o[2048 + t] = (f16)g2[t];
  o[3072 + t] = (f16)be2[t];
}

// W [K][N] fp32 -> Wt [N][K] f16, 64x64 LDS tiles
__global__ __launch_bounds__(256) void transpose_cvt(const float* __restrict__ W,
                                                     f16* __restrict__ Wt, int K,
                                                     int N) {
  __shared__ float tile[64][65];
  const int bn = blockIdx.x * 64;
  const int bk = blockIdx.y * 64;
  const int tx = threadIdx.x & 63;
  const int ty = threadIdx.x >> 6;  // 0..3
#pragma unroll
  for (int i = 0; i < 64; i += 4)
    tile[ty + i][tx] = W[(long long)(bk + ty + i) * N + bn + tx];
  __syncthreads();
#pragma unroll
  for (int i = 0; i < 64; i += 4)
    Wt[(long long)(bn + ty + i) * K + bk + tx] = (f16)tile[tx][ty + i];
}

extern "C" void kernel_launch(void* const* d_in, const int* in_sizes, int n_in,
                              void* d_out, int out_size, void* d_ws, size_t ws_size,
                              hipStream_t stream) {
  const float* desc = (const float*)d_in[0];
  const float* W0 = (const float*)d_in[1];
  const float* b0 = (const float*)d_in[2];
  const float* W1 = (const float*)d_in[3];
  const float* g1 = (const float*)d_in[4];
  const float* be1 = (const float*)d_in[5];
  const float* W2 = (const float*)d_in[6];
  const float* g2 = (const float*)d_in[7];
  const float* be2 = (const float*)d_in[8];
  const float* W3 = (const float*)d_in[9];
  const float* g3 = (const float*)d_in[10];
  const float* be3 = (const float*)d_in[11];
  const float* Wout = (const float*)d_in[12];
  const float* bout = (const float*)d_in[13];
  float* out = (float*)d_out;

  const long long Nrows = 65536, D = 512, W = 1024;
  char* p = (char*)d_ws;
  f16* descH = (f16*)p; p += Nrows * D * sizeof(f16);   // 67.1 MB
  f16* Wt0 = (f16*)p;   p += D * W * sizeof(f16);       // 1 MB
  f16* Wt1 = (f16*)p;   p += W * W * sizeof(f16);       // 2 MB
  f16* Wt2 = (f16*)p;   p += W * W * sizeof(f16);       // 2 MB
  f16* Wt3 = (f16*)p;   p += W * W * sizeof(f16);       // 2 MB
  f16* H = (f16*)p;     p += Nrows * W * sizeof(f16);   // 134.2 MB
  f16* Y = (f16*)p;     p += Nrows * W * sizeof(f16);   // 134.2 MB
  float* S1 = (float*)p; p += Nrows * 2 * sizeof(float);  // 0.5 MB
  float* S2 = (float*)p; p += Nrows * 2 * sizeof(float);  // 0.5 MB
  f16* ghb = (f16*)p;   p += 4096 * sizeof(f16);        // g1,be1,g2,be2 f16
  (void)ws_size; (void)in_sizes; (void)n_in; (void)out_size;

  // stats buffers must be zeroed every call (harness re-poisons ws).
  zero_f32_kernel<<<(int)(Nrows * 4 / 4 / 256), 256, 0, stream>>>(S1, (int)(Nrows * 4));
  cvt_gb_kernel<<<1, 1024, 0, stream>>>(g1, be1, g2, be2, ghb);
  cvt_f16_kernel<<<(int)(Nrows * D / 8 / 256), 256, 0, stream>>>(desc, descH,
                                                                 Nrows * D);
  transpose_cvt<<<dim3(W / 64, D / 64), 256, 0, stream>>>(W0, Wt0, (int)D, (int)W);
  transpose_cvt<<<dim3(W / 64, W / 64), 256, 0, stream>>>(W1, Wt1, (int)W, (int)W);
  transpose_cvt<<<dim3(W / 64, W / 64), 256, 0, stream>>>(W2, Wt2, (int)W, (int)W);
  transpose_cvt<<<dim3(W / 64, W / 64), 256, 0, stream>>>(W3, Wt3, (int)W, (int)W);

  dim3 ggrid(W / TN, Nrows / TM);  // (4, 512)
  // layer 0: H = relu(desc @ W0 + b0)
  gemm_f16<0, 0, 0><<<ggrid, 256, 0, stream>>>(descH, Wt0, b0, nullptr, nullptr,
                                               nullptr, nullptr, H, (int)Nrows,
                                               (int)W, (int)D);
  // layer 1: Y = H @ W1, epilogue accumulates row stats -> S1
  gemm_f16<0, 1, 1><<<ggrid, 256, 0, stream>>>(H, Wt1, nullptr, nullptr, nullptr,
                                               nullptr, S1, Y, (int)Nrows, (int)W,
                                               (int)W);
  // layer 2: A = relu(LN(Y; S1)*g1+be1) on the fly; H2 = A @ W2 -> H, stats -> S2
  gemm_f16<1, 1, 1><<<ggrid, 256, 0, stream>>>(Y, Wt2, nullptr, (const float2*)S1,
                                               ghb, ghb + 1024, S2, H, (int)Nrows,
                                               (int)W, (int)W);
  // layer 3: A = relu(LN(H; S2)*g2+be2) on the fly; Y3 = A @ W3 -> Y
  gemm_f16<1, 1, 0><<<ggrid, 256, 0, stream>>>(H, Wt3, nullptr, (const float2*)S2,
                                               ghb + 2048, ghb + 3072, nullptr, Y,
                                               (int)Nrows, (int)W, (int)W);
  // output: out = relu(dot(relu(LN(Y)*g3+be3), Wout) + bout)
  ln_relu_out_kernel<<<(int)(Nrows / 4), 256, 0, stream>>>(Y, g3, be3, Wout, bout,
                                                           out);
}